// Round 11
// baseline (163.864 us; speedup 1.0000x reference)
//
#include <hip/hip_runtime.h>

// KANN_4578435137547: quadratic Lagrange FEM basis + weight contraction.
// Structure: (1) LOOP-FREE zero-fill — one float4 store per thread,
// 1024-thread blocks (49224 workgroups; 4x fewer CP dispatch packets than
// R9's 256-thread version, identical store stream); (2) fused scatter
// writes the ~1.2 MB of nonzeros.
// Outputs (flat f32): t[32768], dt[32768], ddt[32768],
// phi/dphi/ddphi each [32768][2049].

#define KN_NODES    2049
#define KN_IK       32768                               // 4096 samples * 8 width
#define KN_HEAD     (3 * KN_IK)                         // 98304
#define KN_PHI_LEN  ((size_t)KN_IK * KN_NODES)          // 67,141,632
#define KN_TOT_F4   50405376u                           // 201,621,504 floats / 4
#define KN_FILL_BLK 49224u                              // KN_TOT_F4 / 1024

typedef float kn_f4 __attribute__((ext_vector_type(4)));

// Loop-free fill: thread g zeroes float4 #g. No loop, no branch.
__global__ __launch_bounds__(1024)
void KANN_fill0(kn_f4* __restrict__ p) {
    unsigned g = blockIdx.x * 1024u + threadIdx.x;
    const kn_f4 z = {0.0f, 0.0f, 0.0f, 0.0f};
    p[(size_t)g] = z;
}

__global__ __launch_bounds__(256)
void KANN_scatter(const float* __restrict__ x, const float* __restrict__ w,
                  float* __restrict__ out) {
    int ik = blockIdx.x * 256 + threadIdx.x;
    if (ik >= KN_IK) return;
    int i = ik >> 3, k = ik & 7;

    float xv  = x[i];
    float xs  = 2048.0f * xv;
    float fid = floorf(0.5f * xs);
    fid = fminf(fmaxf(fid, 0.0f), 1023.0f);
    int   nl  = 2 * (int)fid;                 // even, [0, 2046]
    float x_t = xs - (float)nl - 1.0f;        // [-1, 1]

    float p0 = 0.5f * x_t * (x_t - 1.0f);
    float p1 = 1.0f - x_t * x_t;
    float p2 = 0.5f * x_t * (x_t + 1.0f);
    float d0 = (x_t - 0.5f) * 2048.0f;
    float d1 = -4096.0f * x_t;
    float d2 = (x_t + 0.5f) * 2048.0f;
    const float s0 = 4194304.0f, s1 = -8388608.0f;

    const float* wk = w + k * KN_NODES + nl;
    float w0 = wk[0], w1 = wk[1], w2 = wk[2];
    out[ik]             = w0 * p0 + w1 * p1 + w2 * p2;
    out[KN_IK + ik]     = w0 * d0 + w1 * d1 + w2 * d2;
    out[2 * KN_IK + ik] = (w0 - 2.0f * w1 + w2) * 4194304.0f;

    float* pphi = out + KN_HEAD + (size_t)ik * KN_NODES + nl;
    pphi[0] = p0; pphi[1] = p1; pphi[2] = p2;
    float* pd = pphi + KN_PHI_LEN;
    pd[0] = d0; pd[1] = d1; pd[2] = d2;
    float* ps = pd + KN_PHI_LEN;
    ps[0] = s0; ps[1] = s1; ps[2] = s0;
}

extern "C" void kernel_launch(void* const* d_in, const int* in_sizes, int n_in,
                              void* d_out, int out_size, void* d_ws, size_t ws_size,
                              hipStream_t stream) {
    const float* x = (const float*)d_in[0];
    const float* w = (const float*)d_in[1];
    float* out = (float*)d_out;

    KANN_fill0<<<dim3(KN_FILL_BLK), dim3(1024), 0, stream>>>((kn_f4*)out);
    KANN_scatter<<<dim3(KN_IK / 256), dim3(256), 0, stream>>>(x, w, out);
}

// Round 12
// 144.232 us; speedup vs baseline: 1.1361x; 1.1361x over previous
//
#include <hip/hip_runtime.h>

// KANN_4578435137547: quadratic Lagrange FEM basis + weight contraction.
// Structure (best measured, R9): (1) LOOP-FREE zero-fill — one float4 store
// per thread, 256-thread blocks, 196896 workgroups (wave-streaming, mirrors
// rocclr fillBufferAligned; every looped/chunked/nt/column variant measured
// 20-100% slower); (2) fused scatter writes the ~1.2 MB of nonzeros
// (heads + 3-float windows per plane).
// Outputs (flat f32): t[32768], dt[32768], ddt[32768],
// phi/dphi/ddphi each [32768][2049].

#define KN_NODES    2049
#define KN_IK       32768                               // 4096 samples * 8 width
#define KN_HEAD     (3 * KN_IK)                         // 98304
#define KN_PHI_LEN  ((size_t)KN_IK * KN_NODES)          // 67,141,632
#define KN_TOT_F4   50405376u                           // 201,621,504 floats / 4
#define KN_FILL_BLK 196896u                             // KN_TOT_F4 / 256

typedef float kn_f4 __attribute__((ext_vector_type(4)));

// Loop-free fill: thread g zeroes float4 #g. No loop, no branch, VGPR-minimal.
__global__ __launch_bounds__(256)
void KANN_fill0(kn_f4* __restrict__ p) {
    unsigned g = blockIdx.x * 256u + threadIdx.x;
    const kn_f4 z = {0.0f, 0.0f, 0.0f, 0.0f};
    p[(size_t)g] = z;
}

__global__ __launch_bounds__(256)
void KANN_scatter(const float* __restrict__ x, const float* __restrict__ w,
                  float* __restrict__ out) {
    int ik = blockIdx.x * 256 + threadIdx.x;
    if (ik >= KN_IK) return;
    int i = ik >> 3, k = ik & 7;

    float xv  = x[i];
    float xs  = 2048.0f * xv;
    float fid = floorf(0.5f * xs);
    fid = fminf(fmaxf(fid, 0.0f), 1023.0f);
    int   nl  = 2 * (int)fid;                 // even, [0, 2046]
    float x_t = xs - (float)nl - 1.0f;        // [-1, 1]

    float p0 = 0.5f * x_t * (x_t - 1.0f);
    float p1 = 1.0f - x_t * x_t;
    float p2 = 0.5f * x_t * (x_t + 1.0f);
    float d0 = (x_t - 0.5f) * 2048.0f;
    float d1 = -4096.0f * x_t;
    float d2 = (x_t + 0.5f) * 2048.0f;
    const float s0 = 4194304.0f, s1 = -8388608.0f;

    const float* wk = w + k * KN_NODES + nl;
    float w0 = wk[0], w1 = wk[1], w2 = wk[2];
    out[ik]             = w0 * p0 + w1 * p1 + w2 * p2;
    out[KN_IK + ik]     = w0 * d0 + w1 * d1 + w2 * d2;
    out[2 * KN_IK + ik] = (w0 - 2.0f * w1 + w2) * 4194304.0f;

    float* pphi = out + KN_HEAD + (size_t)ik * KN_NODES + nl;
    pphi[0] = p0; pphi[1] = p1; pphi[2] = p2;
    float* pd = pphi + KN_PHI_LEN;
    pd[0] = d0; pd[1] = d1; pd[2] = d2;
    float* ps = pd + KN_PHI_LEN;
    ps[0] = s0; ps[1] = s1; ps[2] = s0;
}

extern "C" void kernel_launch(void* const* d_in, const int* in_sizes, int n_in,
                              void* d_out, int out_size, void* d_ws, size_t ws_size,
                              hipStream_t stream) {
    const float* x = (const float*)d_in[0];
    const float* w = (const float*)d_in[1];
    float* out = (float*)d_out;

    KANN_fill0<<<dim3(KN_FILL_BLK), dim3(256), 0, stream>>>((kn_f4*)out);
    KANN_scatter<<<dim3(KN_IK / 256), dim3(256), 0, stream>>>(x, w, out);
}